// Round 16
// baseline (266.640 us; speedup 1.0000x reference)
//
#include <hip/hip_runtime.h>

// Problem dims (fixed by the reference): B=256, T=100, D=1024, H=128, C=5
constexpr int Bsz = 256;
constexpr int Tn  = 100;
constexpr int Dn  = 1024;
constexpr int Hn  = 128;
constexpr int Cn  = 5;

// float64 values of np.exp(-1/10), np.exp(-1/20)
#define D1 0.9048374180359595731642491
#define D2 0.9512294245007140090914253

typedef short  bf16x8 __attribute__((ext_vector_type(8)));
typedef short  short4v __attribute__((ext_vector_type(4)));
typedef float  f32x4  __attribute__((ext_vector_type(4)));

// ---------------------------------------------------------------------------
// R24: TILE_M=16 on R23's proven coalesced-B structure.
// R23 post-mortem (gemm 81.8us, WIN): MfmaUtil 19.8 matches 19us MFMA
// content / 82us; 800 blocks ~= 794 resident slots -> every block spans the
// dispatch (6000cy/chunk vs ~600cy true chain), Occupancy 26% grid-limited.
// Register audit: VGPR 64 + acc 32 + a64 32 = EXACTLY 128 = the (256,4)
// budget -> zero headroom (this is why R22's dbuf spilled).
// TILE_M 32->16: grid 1600 (6.25/CU vs cap 4 -> CUs sustain full 4-block
// residency), LDS 12.3KB, accumulators halve (c00[2]+c01[2]+a64[2][4] = 32
// regs -> ~90/128 used, real headroom). Per-output math bit-identical to
// R23 (same chunk order, same flush chunks). B re-read x2 but W1F is
// 768KB L2-resident -> HBM FETCH ~unchanged.
// Failure read: occupancy >=45 but gemm ~80 -> per-wave chain binds ->
// next round: B chunk double-buffer in the freed registers.
// ---------------------------------------------------------------------------
constexpr int TILE_M = 16;
constexpr int SC     = 64;            // staging sub-chunk (k)
constexpr int NSUB   = Dn / SC;       // 16
constexpr int NCHUNK = 2;             // K=32 MFMA chunks per sub-chunk
constexpr int FRAGS  = (Dn / 32) * 3 * 2 * 4;        // 768 fragments
constexpr int CHSTR  = 3 * 2 * 4 * 512;              // 12288 shorts per chunk

__device__ __forceinline__ unsigned f2b_bits(float f) {
  union { float f; unsigned u; } c; c.f = f;
  return (c.u + 0x7FFFu + ((c.u >> 16) & 1u)) >> 16;   // RNE f32->bf16
}
__device__ __forceinline__ float b_bits2f(unsigned b) {
  union { unsigned u; float f; } c; c.u = b << 16; return c.f;
}

// ---------------------------------------------------------------------------
// W1 f32 -> fragment-order bf16 planes (R23-proven):
// W1F[((g*3+sp)*2+nt)*4+w][lane=kseg*16+mA][e]  (768 frags x 64 lanes x 8)
// ---------------------------------------------------------------------------
__global__ __launch_bounds__(256) void cvt_w1_frag(const float* __restrict__ W1,
                                                   short* __restrict__ W1F)
{
  const int n  = blockIdx.x;              // 0..127
  const int k0 = threadIdx.x * 4;         // 0..1020 (4 consecutive k)
  const int w  = (n >> 4) & 3;
  const int nt = (n >> 6) & 1;
  const int mA = n & 15;
  const int g    = k0 >> 5;
  const int kseg = (k0 >> 3) & 3;
  const int e0   = k0 & 7;                // 0 or 4

  short4v s0, s1, s2;
  #pragma unroll
  for (int j = 0; j < 4; ++j) {
    const float x = W1[(size_t)(k0 + j) * Hn + n];
    const unsigned u0 = f2b_bits(x);  const float f0 = b_bits2f(u0);
    const float r1 = x - f0;
    const unsigned u1 = f2b_bits(r1); const float f1 = b_bits2f(u1);
    const float r2 = r1 - f1;
    const unsigned u2 = f2b_bits(r2);
    s0[j] = (short)u0; s1[j] = (short)u1; s2[j] = (short)u2;
  }
  const int lane = kseg * 16 + mA;
  #pragma unroll
  for (int sp = 0; sp < 3; ++sp) {
    const int frag = ((g * 3 + sp) * 2 + nt) * 4 + w;
    short4v* dst = (short4v*)(W1F + (size_t)frag * 512 + lane * 8 + e0);
    *dst = (sp == 0) ? s0 : (sp == 1) ? s1 : s2;
  }
}

// ---------------------------------------------------------------------------
__global__ __launch_bounds__(256, 4) void gemm_bf16x3(
    const float* __restrict__ X, const short* __restrict__ W1F,
    double* __restrict__ Hc)
{
  // union: Abf staging (12288B)  <->  hb[16][128] f64 epilogue (16384B)
  __shared__ __align__(16) char smem[16384];
  auto Abf = (short(*)[3][NCHUNK][64][8])smem;   // [buf][sp][kc][lane][e]
  double* hb = (double*)smem;

  const int tid = threadIdx.x;
  const int m0  = blockIdx.x * TILE_M;

  // staging decomposition: 16 rows x 64 k = 256 float4 -> 1 per thread
  const int rA    = tid >> 4;               // row 0..15
  const int c8    = tid & 15;               // float4 k-group, k0 = 4*c8
  const int kcT   = c8 >> 3;                // chunk within sub-chunk
  const int ksegT = (c8 >> 1) & 3;
  const int halfT = c8 & 1;                 // elems 0-3 or 4-7 of the frag
  const int laneT = ksegT * 16 + rA;        // fragment lane this float4 feeds
  const float* Apt = X + (size_t)(m0 + rA) * Dn;

  // compute decomposition: wave w -> n-tiles {w*16, w*16+64}
  const int w    = tid >> 6;
  const int lane = tid & 63;
  const int mA   = lane & 15;
  const int kseg = lane >> 4;
  const int n0   = w * 16;

  // --- bf16 D-layout probe (proven): D[r][c] = r + 16*c -------------------
  int drow[4], dcol[4];
  {
    bf16x8 a, b;
    #pragma unroll
    for (int j = 0; j < 8; ++j) {
      const int k = kseg * 8 + j;
      a[j] = (short)((k == mA) ? 0x3F80 : 0);
      b[j] = (short)f2b_bits((float)(k + 16 * mA));
    }
    f32x4 z = {0.0f, 0.0f, 0.0f, 0.0f};
    z = __builtin_amdgcn_mfma_f32_16x16x32_bf16(a, b, z, 0, 0, 0);
    #pragma unroll
    for (int r = 0; r < 4; ++r) {
      const int p = (int)z[r];
      drow[r] = p & 15;
      dcol[r] = p >> 4;
    }
  }

  // accumulators: dominant stream c00 (f32 chain, f64-flushed), minor c01
  f32x4 c00[2], c01[2];
  double a64[2][4];
  #pragma unroll
  for (int nt = 0; nt < 2; ++nt) {
    c00[nt] = (f32x4){0.f, 0.f, 0.f, 0.f};
    c01[nt] = (f32x4){0.f, 0.f, 0.f, 0.f};
    #pragma unroll
    for (int r = 0; r < 4; ++r) a64[nt][r] = 0.0;
  }

  // B fragment base pointers — fragment-order layout, lane-coalesced 16B
  const short* bbase[3][2];
  #pragma unroll
  for (int sp = 0; sp < 3; ++sp)
    #pragma unroll
    for (int nt = 0; nt < 2; ++nt)
      bbase[sp][nt] = W1F + (size_t)((sp * 2 + nt) * 4 + w) * 512 + lane * 8;

  // prefetch sub-chunk 0: 1 float4 per thread (16 m x 64 k / 256 thr)
  float4 pf = *(const float4*)(Apt + 4 * c8);

  int buf = 0;
  for (int s = 0; s < NSUB; ++s) {
    // ---- staging: split each f32 ONCE into 3 bf16 planes, frag layout ----
    {
      const float xv[4] = {pf.x, pf.y, pf.z, pf.w};
      short4v s0, s1, s2;
      #pragma unroll
      for (int e = 0; e < 4; ++e) {
        const unsigned u0 = f2b_bits(xv[e]); const float f0 = b_bits2f(u0);
        const float r1 = xv[e] - f0;                       // exact
        const unsigned u1 = f2b_bits(r1);    const float f1 = b_bits2f(u1);
        const float r2 = r1 - f1;                          // exact
        const unsigned u2 = f2b_bits(r2);
        s0[e] = (short)u0; s1[e] = (short)u1; s2[e] = (short)u2;
      }
      *(short4v*)&Abf[buf][0][kcT][laneT][4 * halfT] = s0;
      *(short4v*)&Abf[buf][1][kcT][laneT][4 * halfT] = s1;
      *(short4v*)&Abf[buf][2][kcT][laneT][4 * halfT] = s2;
    }
    __syncthreads();

    // prefetch next sub-chunk (overlaps compute)
    if (s + 1 < NSUB)
      pf = *(const float4*)(Apt + (s + 1) * SC + 4 * c8);

    #pragma unroll
    for (int kc = 0; kc < NCHUNK; ++kc) {
      const int g = s * NCHUNK + kc;           // global K=32 chunk 0..31

      // B fragments: one fully-coalesced 1KB wave-load each (L2-resident)
      bf16x8 bfr[3][2];
      #pragma unroll
      for (int sp = 0; sp < 3; ++sp)
        #pragma unroll
        for (int nt = 0; nt < 2; ++nt)
          bfr[sp][nt] = *(const bf16x8*)(bbase[sp][nt] + (size_t)g * CHSTR);

      // A fragments: one conflict-free ds_read_b128 per plane, then 12 MFMA
      const bf16x8 a0 = *(const bf16x8*)&Abf[buf][0][kc][lane][0];
      const bf16x8 a1 = *(const bf16x8*)&Abf[buf][1][kc][lane][0];
      const bf16x8 a2 = *(const bf16x8*)&Abf[buf][2][kc][lane][0];
      #pragma unroll
      for (int nt = 0; nt < 2; ++nt) {
        c00[nt] = __builtin_amdgcn_mfma_f32_16x16x32_bf16(a0, bfr[0][nt], c00[nt], 0, 0, 0);
        c01[nt] = __builtin_amdgcn_mfma_f32_16x16x32_bf16(a0, bfr[1][nt], c01[nt], 0, 0, 0);
        c01[nt] = __builtin_amdgcn_mfma_f32_16x16x32_bf16(a1, bfr[0][nt], c01[nt], 0, 0, 0);
        c01[nt] = __builtin_amdgcn_mfma_f32_16x16x32_bf16(a1, bfr[1][nt], c01[nt], 0, 0, 0);
        c01[nt] = __builtin_amdgcn_mfma_f32_16x16x32_bf16(a0, bfr[2][nt], c01[nt], 0, 0, 0);
        c01[nt] = __builtin_amdgcn_mfma_f32_16x16x32_bf16(a2, bfr[0][nt], c01[nt], 0, 0, 0);
      }

      // f64 flush of the dominant stream every 8 chunks (same as R20-R23)
      if ((g & 7) == 7) {
        #pragma unroll
        for (int nt = 0; nt < 2; ++nt) {
          #pragma unroll
          for (int r = 0; r < 4; ++r)
            a64[nt][r] += (double)c00[nt][r];
          c00[nt] = (f32x4){0.f, 0.f, 0.f, 0.f};
        }
      }
    }
    buf ^= 1;
  }

  // ---- epilogue: combine in f64 via LDS, coalesced stores ----------------
  __syncthreads();                   // staging reads done before hb alias
  #pragma unroll
  for (int nt = 0; nt < 2; ++nt)
    #pragma unroll
    for (int r = 0; r < 4; ++r) {
      const double h = a64[nt][r] + (double)c00[nt][r] + (double)c01[nt][r];
      hb[drow[r] * Hn + (n0 + nt * 64 + dcol[r])] = h;
    }
  __syncthreads();
  double* dst = Hc + (size_t)m0 * Hn;
  #pragma unroll
  for (int i = tid; i < TILE_M * Hn / 2; i += 256)
    *(double2*)(dst + 2 * i) = *(const double2*)(hb + 2 * i);
}

// ---------------------------------------------------------------------------
// Phase 2 scan v3 — UNCHANGED (proven ~10us).
// ---------------------------------------------------------------------------
constexpr int THALF = 50;

__global__ __launch_bounds__(256) void snn_scan_v3(
    const double* __restrict__ Hc, const float* __restrict__ b1,
    const float* __restrict__ W2, const float* __restrict__ b2,
    float* __restrict__ out)
{
#pragma clang fp contract(off)
  __shared__ __align__(16) double HcL[THALF * Hn];        // 51200 B
  __shared__ double W2d[Hn * Cn];                          // 5120 B
  __shared__ double Pp[Tn * Cn];                           // 4000 B
  __shared__ unsigned long long Mk[Tn][2];                 // 1600 B

  const int b   = blockIdx.x;
  const int tid = threadIdx.x;

  for (int i = tid; i < Hn * Cn; i += 256)
    W2d[i] = (double)W2[i];

  const int j0 = (tid & 63) * 2;
  const double b1a = (double)b1[j0];
  const double b1b = (double)b1[j0 + 1];
  double v1a = 0.0, v1b = 0.0;

  const double* hsrc = Hc + (size_t)b * Tn * Hn;

  for (int h = 0; h < 2; ++h) {
    if (h) __syncthreads();

    {
      const double* src = hsrc + (size_t)h * THALF * Hn;
      const int nd2 = THALF * (Hn / 2);
      int i = tid;
      for (; i + 3 * 256 < nd2; i += 4 * 256) {
        double2 a0 = *(const double2*)(src + 2 * (i + 0 * 256));
        double2 a1 = *(const double2*)(src + 2 * (i + 1 * 256));
        double2 a2 = *(const double2*)(src + 2 * (i + 2 * 256));
        double2 a3 = *(const double2*)(src + 2 * (i + 3 * 256));
        *(double2*)&HcL[2 * (i + 0 * 256)] = a0;
        *(double2*)&HcL[2 * (i + 1 * 256)] = a1;
        *(double2*)&HcL[2 * (i + 2 * 256)] = a2;
        *(double2*)&HcL[2 * (i + 3 * 256)] = a3;
      }
      for (; i < nd2; i += 256)
        *(double2*)&HcL[2 * i] = *(const double2*)(src + 2 * i);
    }
    __syncthreads();

    if (tid < 64) {
      const int lane = tid;
      double2 hnext = *(const double2*)&HcL[j0];
      for (int t = 0; t < THALF; ++t) {
        const double2 hc = hnext;
        const int tn = (t + 1 < THALF) ? (t + 1) : t;
        hnext = *(const double2*)&HcL[tn * Hn + j0];

        v1a = (v1a * D1 + hc.x) + b1a;
        v1b = (v1b * D1 + hc.y) + b1b;
        const bool ca = (v1a >= 1.0);
        const bool cb = (v1b >= 1.0);
        const unsigned long long mA = __ballot(ca);
        const unsigned long long mB = __ballot(cb);
        if (ca) v1a = 0.0;
        if (cb) v1b = 0.0;
        if (lane == 0) { Mk[h * THALF + t][0] = mA; Mk[h * THALF + t][1] = mB; }
      }
    }
  }
  __syncthreads();

  for (int pi = tid; pi < Tn * Cn; pi += 256) {
    const int tt = pi / Cn;
    const int cc = pi - tt * Cn;
    const unsigned long long mA = Mk[tt][0];
    const unsigned long long mB = Mk[tt][1];
    double sA = 0.0, sB = 0.0;
    #pragma unroll
    for (int L = 0; L < 64; ++L) {
      sA += ((mA >> L) & 1ull) ? W2d[(2 * L) * Cn + cc]     : 0.0;
      sB += ((mB >> L) & 1ull) ? W2d[(2 * L + 1) * Cn + cc] : 0.0;
    }
    Pp[pi] = sA + sB;
  }
  __syncthreads();

  if (tid < Cn) {
    const int c = tid;
    const double bb2 = (double)b2[c];
    double v2 = 0.0, acc = 0.0;
    double pn = Pp[c];
    for (int t = 0; t < Tn; ++t) {
      const double p = pn;
      const int tn = (t + 1 < Tn) ? (t + 1) : t;
      pn = Pp[tn * Cn + c];
      const double v = ((v2 * D2) + p) + bb2;
      const bool s2 = (v >= 1.0);
      v2 = s2 ? 0.0 : v;
      acc += s2 ? 1.0 : 0.0;
    }
    out[(size_t)b * Cn + c] = (float)(acc / 100.0);
  }
}

// ---------------------------------------------------------------------------
extern "C" void kernel_launch(void* const* d_in, const int* in_sizes, int n_in,
                              void* d_out, int out_size, void* d_ws, size_t ws_size,
                              hipStream_t stream) {
  const float* X  = (const float*)d_in[0];   // [B,T,D]
  const float* W1 = (const float*)d_in[1];   // [D,H]
  const float* b1 = (const float*)d_in[2];   // [H]
  const float* W2 = (const float*)d_in[3];   // [H,C]
  const float* b2 = (const float*)d_in[4];   // [C]
  float* out = (float*)d_out;                // [B,C]

  // ws = W1F bf16 frag-order [768][64][8] (768KB) | Hc f64 [B*Tn, H] (26.2MB)
  short*  W1F = (short*)d_ws;
  double* Hc  = (double*)((char*)d_ws + (size_t)FRAGS * 512 * sizeof(short));

  cvt_w1_frag<<<dim3(Hn), dim3(256), 0, stream>>>(W1, W1F);
  gemm_bf16x3<<<dim3(Bsz * Tn / TILE_M), dim3(256), 0, stream>>>(X, W1F, Hc);
  snn_scan_v3<<<dim3(Bsz), dim3(256), 0, stream>>>(Hc, b1, W2, b2, out);
}